// Round 2
// baseline (119.519 us; speedup 1.0000x reference)
//
#include <hip/hip_runtime.h>
#include <cfloat>

// Problem constants (from reference setup_inputs)
constexpr int B = 4;
constexpr int N = 8192;          // points per cloud (pred and gt both 8192)
constexpr int Q = 8;             // query points per thread
constexpr int BLK = 256;         // threads per block
constexpr int QPB = Q * BLK;     // 2048 queries per block
constexpr int NQG = N / QPB;     // 4 query groups per batch
constexpr int CHUNK = 512;       // target points staged per block
constexpr int NCH = N / CHUNK;   // 16 target chunks
constexpr int DIR_BLOCKS = B * NQG * NCH;   // 256
constexpr int MAIN_BLOCKS = 2 * DIR_BLOCKS; // 512 (both directions in one launch)

// ws layout: uint mins[2][B][N] (min distances as float bit patterns)
constexpr int MINS_ELEMS = 2 * B * N;       // 65536

__global__ __launch_bounds__(BLK) void chamfer_main(
        const float* __restrict__ pred, const float* __restrict__ gt,
        unsigned int* __restrict__ mins) {
    int bid = blockIdx.x;
    int dir = bid / DIR_BLOCKS;       // 0: query=pred,target=gt -> min1 ; 1: swapped -> min2
    int r   = bid % DIR_BLOCKS;
    int b   = r / (NQG * NCH);
    int r2  = r % (NQG * NCH);
    int qg  = r2 / NCH;
    int ch  = r2 % NCH;

    const float* qry = dir ? gt : pred;
    const float* tgt = dir ? pred : gt;
    unsigned int* omin = mins + dir * (B * N) + b * N;

    // Stage target chunk as (-2x, -2y, -2z, |g|^2): inner loop is then
    // t = dot3(p, g') + |g|^2 via 3 fma; d = t + |p|^2 folded out of loop.
    __shared__ float4 s[CHUNK];
    const float* tbase = tgt + (size_t)b * N * 3 + (size_t)ch * CHUNK * 3;
    for (int j = threadIdx.x; j < CHUNK; j += BLK) {
        float x = tbase[j * 3 + 0];
        float y = tbase[j * 3 + 1];
        float z = tbase[j * 3 + 2];
        s[j] = make_float4(-2.f * x, -2.f * y, -2.f * z,
                           fmaf(x, x, fmaf(y, y, z * z)));
    }
    __syncthreads();

    // Load Q query points per thread (stride BLK for coalescing)
    float px[Q], py[Q], pz[Q], pn[Q], mn[Q];
    const float* qbase = qry + (size_t)b * N * 3 + (size_t)qg * QPB * 3;
#pragma unroll
    for (int q = 0; q < Q; ++q) {
        int qi = threadIdx.x + q * BLK;
        px[q] = qbase[qi * 3 + 0];
        py[q] = qbase[qi * 3 + 1];
        pz[q] = qbase[qi * 3 + 2];
        pn[q] = fmaf(px[q], px[q], fmaf(py[q], py[q], pz[q] * pz[q]));
        mn[q] = FLT_MAX;
    }

    // Inner loop: 2 targets per step; fminf(fminf(t0,t1), mn) encourages
    // v_min3_f32 fusion -> 3.5 VALU instr per pair. LDS reads are wave-wide
    // broadcasts (conflict-free): 2 x b128 per 56 VALU instrs.
#pragma unroll 2
    for (int j = 0; j < CHUNK; j += 2) {
        float4 g0 = s[j];
        float4 g1 = s[j + 1];
#pragma unroll
        for (int q = 0; q < Q; ++q) {
            float t0 = fmaf(px[q], g0.x, fmaf(py[q], g0.y, fmaf(pz[q], g0.z, g0.w)));
            float t1 = fmaf(px[q], g1.x, fmaf(py[q], g1.y, fmaf(pz[q], g1.z, g1.w)));
            mn[q] = fminf(fminf(t0, t1), mn[q]);   // -> v_min3_f32
        }
    }

#pragma unroll
    for (int q = 0; q < Q; ++q) {
        float d = fmaxf(mn[q] + pn[q], 0.f);   // clamp: keeps uint-bit ordering valid
        int qi = qg * QPB + threadIdx.x + q * BLK;
        atomicMin(&omin[qi], __float_as_uint(d));
    }
}

// Single-block final reduction: 8 segments of N values each -> 2 scalars.
__global__ __launch_bounds__(256) void reduce_all(
        const unsigned int* __restrict__ mins, float* __restrict__ out) {
    __shared__ float ssum[256], smax[256];
    float csum = 0.f, hsum = 0.f;
#pragma unroll 1
    for (int a = 0; a < 2 * B; ++a) {
        const unsigned int* base = mins + (size_t)a * N;
        float sum = 0.f, mx = -FLT_MAX;
        for (int i = threadIdx.x; i < N; i += 256) {
            float v = __uint_as_float(base[i]);
            sum += v;
            mx = fmaxf(mx, v);
        }
        ssum[threadIdx.x] = sum;
        smax[threadIdx.x] = mx;
        __syncthreads();
        for (int st = 128; st > 0; st >>= 1) {
            if (threadIdx.x < st) {
                ssum[threadIdx.x] += ssum[threadIdx.x + st];
                smax[threadIdx.x] = fmaxf(smax[threadIdx.x], smax[threadIdx.x + st]);
            }
            __syncthreads();
        }
        csum += ssum[0];
        hsum += smax[0];
        __syncthreads();   // before next segment reuses ssum/smax
    }
    if (threadIdx.x == 0) {
        // chamfer = mean_b(mean_n min1 + mean_m min2) = (sum of all)/(B*N)
        out[0] = csum / (float)(B * N);
        // hausdorff = mean_b(max min1) + mean_b(max min2) = (sum of 8 maxes)/B
        out[1] = hsum / (float)B;
    }
}

extern "C" void kernel_launch(void* const* d_in, const int* in_sizes, int n_in,
                              void* d_out, int out_size, void* d_ws, size_t ws_size,
                              hipStream_t stream) {
    const float* pred = (const float*)d_in[0];
    const float* gt   = (const float*)d_in[1];
    float* out = (float*)d_out;

    unsigned int* mins = (unsigned int*)d_ws;

    // 0xFFFFFFFF compares greater than any clamped non-negative float bits.
    hipMemsetAsync(mins, 0xFF, (size_t)MINS_ELEMS * sizeof(unsigned int), stream);
    chamfer_main<<<MAIN_BLOCKS, BLK, 0, stream>>>(pred, gt, mins);
    reduce_all<<<1, 256, 0, stream>>>(mins, out);
}